// Round 1
// baseline (1327.312 us; speedup 1.0000x reference)
//
#include <hip/hip_runtime.h>
#include <math.h>

#define Bsz 512
#define Fsz 64
#define Hsz 256
#define TSTEPS 128
#define G3 768

#define BG 16            // batch groups (32 rows each)
#define HB 16            // hidden-slice blocks (16 cols x 3 gates each)
#define NBLK 256
#define NTHR 256

// LDS: double-buffered K-reduction scratch + biases.
// per buffer: 32 gate slots (4 waves x 2 m x 4 gates) + 8 oa slots; slot = 64 lanes x f32x4
#define RED_SLOTS 40
#define OFF_B (2*RED_SLOTS*64*16)      // 81920
#define SMEM_BYTES (OFF_B + 512)

typedef float f32x4 __attribute__((ext_vector_type(4)));
typedef short s16x8 __attribute__((ext_vector_type(8)));
typedef unsigned int  u32x4 __attribute__((ext_vector_type(4)));

#define MF(a,b,c) __builtin_amdgcn_mfma_f32_16x16x32_bf16(a,b,c,0,0,0)

static __device__ __forceinline__ unsigned short bf16_rne(float f){
    union { float f; unsigned u; } v; v.f = f;
    return (unsigned short)((v.u + 0x7FFFu + ((v.u >> 16) & 1u)) >> 16);
}
static __device__ __forceinline__ float bf16_to_f(unsigned short h){
    union { unsigned u; float f; } v; v.u = ((unsigned)h) << 16; return v.f;
}
static __device__ __forceinline__ void split8(const float* p, s16x8& hi, s16x8& lo){
    #pragma unroll
    for (int t = 0; t < 8; ++t){
        float f = p[t];
        unsigned short h = bf16_rne(f);
        hi[t] = (short)h;
        lo[t] = (short)bf16_rne(f - bf16_to_f(h));
    }
}
static __device__ __forceinline__ float sigmoidf_(float v){ return 1.0f/(1.0f + expf(-v)); }

// ---- MALL-coherent (cache-bypass) ops: sc0 sc1 = coherent at LLC ----
__device__ __forceinline__ u32x4 load_sys_b128u(const unsigned* p){
    u32x4 r;
    asm volatile("global_load_dwordx4 %0, %1, off sc0 sc1" : "=v"(r) : "v"(p) : "memory");
    return r;
}
__device__ __forceinline__ unsigned load_sys_b32u_nw(const unsigned* p){
    unsigned r;
    asm volatile("global_load_dword %0, %1, off sc0 sc1" : "=v"(r) : "v"(p) : "memory");
    return r;
}
__device__ __forceinline__ void store_sys_b32u(unsigned* p, unsigned v){
    asm volatile("global_store_dword %0, %1, off sc0 sc1" :: "v"(p), "v"(v) : "memory");
}
__device__ __forceinline__ int load_sys_i32(const int* p){
    int r;
    asm volatile("global_load_dword %0, %1, off sc0 sc1\n\ts_waitcnt vmcnt(0)"
                 : "=v"(r) : "v"(p) : "memory");
    return r;
}
__device__ __forceinline__ void waitcnt0(){ asm volatile("s_waitcnt vmcnt(0)" ::: "memory"); }
// register barrier: pins ALU uses of asm-load results after a preceding waitcnt
__device__ __forceinline__ void regbar(u32x4& v){ asm volatile("" : "+v"(v)); }
__device__ __forceinline__ void regbar32(unsigned& v){ asm volatile("" : "+v"(v)); }

static __device__ __forceinline__ void unpack8(const u32x4 a, const u32x4 b, s16x8& hi, s16x8& lo){
    #pragma unroll
    for (int e = 0; e < 4; ++e){
        hi[e]   = (short)(a[e] >> 16);  lo[e]   = (short)(a[e] & 0xFFFFu);
        hi[4+e] = (short)(b[e] >> 16);  lo[4+e] = (short)(b[e] & 0xFFFFu);
    }
}

// ---------------- setup: M = dec_Wih@reg_W, cfold = dec_Wih@reg_b + dec_bih,
// ---------------- gi0 = x[:,127,:]@dec_Wih.T + dec_bih
extern "C" __global__ void gru_setup(const float* __restrict__ x,
                                     const float* __restrict__ dWih,
                                     const float* __restrict__ dbih,
                                     const float* __restrict__ regW,
                                     const float* __restrict__ regb,
                                     float* __restrict__ Mw,
                                     float* __restrict__ cfold,
                                     float* __restrict__ gi0)
{
    int idx = blockIdx.x*blockDim.x + threadIdx.x;
    if (idx < G3*Hsz) {
        int g = idx >> 8, j = idx & 255;
        float a = 0.f;
        #pragma unroll 8
        for (int f = 0; f < Fsz; ++f) a += dWih[g*Fsz + f]*regW[f*Hsz + j];
        Mw[idx] = a;
    } else if (idx < G3*Hsz + G3) {
        int g = idx - G3*Hsz;
        float a = dbih[g];
        #pragma unroll 8
        for (int f = 0; f < Fsz; ++f) a += dWih[g*Fsz + f]*regb[f];
        cfold[g] = a;
    } else {
        int e = idx - (G3*Hsz + G3);
        if (e < Bsz*G3) {
            int b = e / G3, g = e - b*G3;
            const float* xp = x + (size_t)b*(256*64) + 127*64;
            float a = dbih[g];
            #pragma unroll 8
            for (int f = 0; f < Fsz; ++f) a += xp[f]*dWih[g*Fsz + f];
            gi0[e] = a;
        }
    }
}

// ---------------- persistent GRU kernel: tag-in-data sync, no LDS staging ----------------
// h word = hi_bf16<<16 | (lo_bf16 & ~3) | tag2, tag2 = ((gen)>>1)&3, slot = gen&1.
// Ring-2 safety: a block writes gen g+1 only after fully reading gen g (per-word tag check),
// which transitively implies every block finished reading gen g-1 -> its slot is dead.
extern "C" __global__ void __launch_bounds__(NTHR, 1)
gru_persistent(const float* __restrict__ x,
               const float* __restrict__ eWih, const float* __restrict__ eWhh,
               const float* __restrict__ ebih, const float* __restrict__ ebhh,
               const float* __restrict__ dWhh, const float* __restrict__ dbhh,
               const float* __restrict__ Mw,   const float* __restrict__ cfold,
               const float* __restrict__ gi0,  const float* __restrict__ regW,
               const float* __restrict__ regb,
               unsigned* __restrict__ hbuf, unsigned* __restrict__ canary,
               float* __restrict__ out)
{
    extern __shared__ char lds[];
    f32x4* s_redv = (f32x4*)lds;
    float* s_bias = (float*)(lds + OFF_B);    // enc: [0..63]; dec: bc [0..47]
    float* s_dbh  = s_bias + 64;              // dec: dbhh slices
    float* s_b3   = s_bias + 112;             // reg_b slice [0..3]

    const int tid  = threadIdx.x;
    const int wv   = tid >> 6;        // wave 0..3 (K-split-4 over K=256)
    const int lane = tid & 63;
    const int quad = lane >> 4;
    const int lcol = lane & 15;
    const int bg   = blockIdx.x >> 4;
    const int hb   = blockIdx.x & 15;
    const int hcol = hb*16 + lcol;
    const int mw   = wv & 1;          // this wave's m for x-GEMM + elementwise
    const int kh   = wv >> 1;         // this wave's k-half for x-GEMM
    const int jb   = kh*2;            // elementwise j-base (0 or 2)
    const int hr0  = mw*16 + quad*4 + jb;   // first of this thread's 2 output rows
    const f32x4 z4 = {0.f, 0.f, 0.f, 0.f};

    // per-wave canary hint word (monotone gen counter); 16B stride
    unsigned* mycan = canary + ((size_t)bg*64 + hb*4 + wv)*4;
    const int* canp = (const int*)canary + ((size_t)bg*64 + lane)*4;
    const int  can_mine = ((lane >> 2) == hb);   // skip own block's canaries

    // ---- encoder weight fragments (B-operand: n=lcol -> row of W, k contiguous) ----
    s16x8 wfh[3][2], wfl[3][2];   // Whh (enc), then dec Whh / combined Whh+M
    s16x8 ufh[3], ufl[3];         // enc Wih (this wave's k-half); dec: [0..1] = M (n-gate)
    s16x8 rwh[2], rwl[2];         // dec: regW rows hb*4+(lcol&3), this wave's k-slice
    #pragma unroll
    for (int g = 0; g < 3; ++g){
        #pragma unroll
        for (int q = 0; q < 2; ++q)
            split8(eWhh + (size_t)(g*256 + hcol)*256 + wv*64 + q*32 + quad*8,
                   wfh[g][q], wfl[g][q]);
        split8(eWih + (size_t)(g*256 + hcol)*64 + kh*32 + quad*8, ufh[g], ufl[g]);
    }
    if (tid < 16){
        int c = hb*16 + tid;
        s_bias[tid]    = ebih[c]       + ebhh[c];
        s_bias[16+tid] = ebih[256+c]   + ebhh[256+c];
        s_bias[32+tid] = ebih[512+c];
        s_bias[48+tid] = ebhh[512+c];
    }
    __syncthreads();

    // =================== unified generation loop ===================
    // g=0..127: encoder (reads h^g, writes h^{g+1}); g=128..255: decoder; g=256: final out only
    for (int g = 0; g <= 2*TSTEPS; ++g){
        const bool enc  = (g < TSTEPS);
        const bool last = (g == 2*TSTEPS);
        const int  p    = g & 1;
        const unsigned tag  = (unsigned)((g >> 1) & 3);
        const unsigned otag = (unsigned)(((g+1) >> 1) & 3);
        const unsigned* hin = hbuf + (size_t)(g & 1)*Bsz*Hsz;
        unsigned* hout = hbuf + (size_t)((g+1) & 1)*Bsz*Hsz;

        // ---- enc->dec transition: reload weights/biases (one-time) ----
        if (g == TSTEPS){
            #pragma unroll
            for (int gg = 0; gg < 3; ++gg)
                #pragma unroll
                for (int q = 0; q < 2; ++q)
                    split8(dWhh + (size_t)(gg*256 + hcol)*256 + wv*64 + q*32 + quad*8,
                           wfh[gg][q], wfl[gg][q]);
            #pragma unroll
            for (int q = 0; q < 2; ++q){
                split8(Mw   + (size_t)(2*256 + hcol)*256 + wv*64 + q*32 + quad*8,
                       ufh[q], ufl[q]);
                split8(regW + (size_t)(hb*4 + (lcol & 3))*256 + wv*64 + q*32 + quad*8,
                       rwh[q], rwl[q]);
            }
            if (tid < 16){
                int c = hb*16 + tid;
                s_bias[tid]    = cfold[c]     + dbhh[c];
                s_bias[16+tid] = cfold[256+c] + dbhh[256+c];
                s_bias[32+tid] = cfold[512+c];
                s_dbh[tid]     = dbhh[c];
                s_dbh[16+tid]  = dbhh[256+c];
                s_dbh[32+tid]  = dbhh[512+c];
            }
            if (tid < 4) s_b3[tid] = regb[hb*4 + tid];
            __syncthreads();
        }
        if (g == TSTEPS + 1){
            // fold M into Whh for R,Z gates: one 3-term MFMA group instead of two
            #pragma unroll
            for (int gg = 0; gg < 2; ++gg)
                #pragma unroll
                for (int q = 0; q < 2; ++q){
                    float tmp[8];
                    const float* pa = dWhh + (size_t)(gg*256 + hcol)*256 + wv*64 + q*32 + quad*8;
                    const float* pb = Mw   + (size_t)(gg*256 + hcol)*256 + wv*64 + q*32 + quad*8;
                    #pragma unroll
                    for (int t2 = 0; t2 < 8; ++t2) tmp[t2] = pa[t2] + pb[t2];
                    split8(tmp, wfh[gg][q], wfl[gg][q]);
                }
        }

        // ---- accumulator init (wave 0 carries biases / gi0; others zero) ----
        f32x4 aR[2], aZ[2], aNi[2], aNh[2], oa[2];
        oa[0] = z4; oa[1] = z4;
        if (wv == 0 && !last){
            if (g == TSTEPS){
                #pragma unroll
                for (int m = 0; m < 2; ++m)
                    #pragma unroll
                    for (int j = 0; j < 4; ++j){
                        int grow_ = bg*32 + m*16 + quad*4 + j;
                        const float* gp = gi0 + (size_t)grow_*G3 + hcol;
                        aR[m][j]  = gp[0]   + s_dbh[lcol];
                        aZ[m][j]  = gp[256] + s_dbh[16+lcol];
                        aNi[m][j] = gp[512];
                        aNh[m][j] = s_dbh[32+lcol];
                    }
            } else {
                float bR = s_bias[lcol], bZ = s_bias[16+lcol], bNi = s_bias[32+lcol];
                float bNh = enc ? s_bias[48+lcol] : s_dbh[32+lcol];
                #pragma unroll
                for (int m = 0; m < 2; ++m){
                    aR[m] = (f32x4){bR,bR,bR,bR}; aZ[m] = (f32x4){bZ,bZ,bZ,bZ};
                    aNi[m] = (f32x4){bNi,bNi,bNi,bNi}; aNh[m] = (f32x4){bNh,bNh,bNh,bNh};
                }
            }
        } else {
            #pragma unroll
            for (int m = 0; m < 2; ++m){ aR[m]=z4; aZ[m]=z4; aNi[m]=z4; aNh[m]=z4; }
        }

        // ---- x loads (enc): per-lane direct, overlapped with canary wait ----
        f32x4 xv0, xv1;
        if (enc){
            const float* xp = x + (size_t)(bg*32 + mw*16 + lcol)*(256*64)
                                + (size_t)g*64 + kh*32 + quad*8;
            xv0 = *(const f32x4*)xp;
            xv1 = *(const f32x4*)(xp + 4);
        }

        // ---- canary wait: cheap hint that producers have issued gen g ----
        if (g){
            while (1){
                int v = load_sys_i32(canp);
                if (__all(can_mine | (v >= g))) break;
                __builtin_amdgcn_s_sleep(1);
            }
        }

        // ---- issue A-fragment loads (per-lane, straight from MALL) ----
        const unsigned* ab = hin + (size_t)(bg*32 + lcol)*256 + wv*64 + quad*8;
        u32x4 t[8];
        #pragma unroll
        for (int m = 0; m < 2; ++m)
            #pragma unroll
            for (int q = 0; q < 2; ++q)
                #pragma unroll
                for (int h4 = 0; h4 < 2; ++h4)
                    t[m*4+q*2+h4] = load_sys_b128u(ab + m*4096 + q*32 + h4*4);
        const unsigned* hoA = hin + (size_t)(bg*32 + hr0)*256 + hcol;
        unsigned ho0 = load_sys_b32u_nw(hoA);
        unsigned ho1 = load_sys_b32u_nw(hoA + 256);

        // ---- x-GEMM while fragments are in flight (enc; m=mw, k-half=kh) ----
        if (enc){
            float xf[8];
            #pragma unroll
            for (int e = 0; e < 4; ++e){ xf[e] = xv0[e]; xf[4+e] = xv1[e]; }
            s16x8 xh, xl;
            split8(xf, xh, xl);
            #define XMF(M) { \
                aR[M] =MF(xh,ufh[0],aR[M]);  aR[M] =MF(xh,ufl[0],aR[M]);  aR[M] =MF(xl,ufh[0],aR[M]);  \
                aZ[M] =MF(xh,ufh[1],aZ[M]);  aZ[M] =MF(xh,ufl[1],aZ[M]);  aZ[M] =MF(xl,ufh[1],aZ[M]);  \
                aNi[M]=MF(xh,ufh[2],aNi[M]); aNi[M]=MF(xh,ufl[2],aNi[M]); aNi[M]=MF(xl,ufh[2],aNi[M]); }
            if (mw == 0) XMF(0) else XMF(1)
            #undef XMF
        }

        // ---- tag spin: re-poll only words whose generation tag doesn't match ----
        {
            unsigned done = 0;
            while (1){
                waitcnt0();
                #pragma unroll
                for (int jj = 0; jj < 8; ++jj) regbar(t[jj]);
                regbar32(ho0); regbar32(ho1);
                unsigned nd = done;
                #pragma unroll
                for (int jj = 0; jj < 8; ++jj)
                    if (!((nd >> jj) & 1u))
                        if (((t[jj][0]&3u)==tag) && ((t[jj][1]&3u)==tag) &&
                            ((t[jj][2]&3u)==tag) && ((t[jj][3]&3u)==tag)) nd |= (1u << jj);
                if (!((nd >> 8) & 1u) && ((ho0 & 3u) == tag)) nd |= 0x100u;
                if (!((nd >> 9) & 1u) && ((ho1 & 3u) == tag)) nd |= 0x200u;
                done = nd;
                if (__all((int)(done == 0x3FFu))) break;
                __builtin_amdgcn_s_sleep(1);
                #pragma unroll
                for (int m = 0; m < 2; ++m)
                    #pragma unroll
                    for (int q = 0; q < 2; ++q)
                        #pragma unroll
                        for (int h4 = 0; h4 < 2; ++h4){
                            const int jj = m*4+q*2+h4;
                            if (!((done >> jj) & 1u))
                                t[jj] = load_sys_b128u(ab + m*4096 + q*32 + h4*4);
                        }
                if (!((done >> 8) & 1u)) ho0 = load_sys_b32u_nw(hoA);
                if (!((done >> 9) & 1u)) ho1 = load_sys_b32u_nw(hoA + 256);
            }
        }

        // ---- h-GEMMs on this wave's K-slice (in-register unpack, no LDS) ----
        #pragma unroll
        for (int m = 0; m < 2; ++m){
            #pragma unroll
            for (int q = 0; q < 2; ++q){
                s16x8 ah, al;
                unpack8(t[m*4+q*2], t[m*4+q*2+1], ah, al);
                if (!last){
                    aR[m]=MF(ah,wfh[0][q],aR[m]); aR[m]=MF(ah,wfl[0][q],aR[m]); aR[m]=MF(al,wfh[0][q],aR[m]);
                    aZ[m]=MF(ah,wfh[1][q],aZ[m]); aZ[m]=MF(ah,wfl[1][q],aZ[m]); aZ[m]=MF(al,wfh[1][q],aZ[m]);
                    aNh[m]=MF(ah,wfh[2][q],aNh[m]); aNh[m]=MF(ah,wfl[2][q],aNh[m]); aNh[m]=MF(al,wfh[2][q],aNh[m]);
                    if (!enc && g > TSTEPS){
                        aNi[m]=MF(ah,ufh[q],aNi[m]); aNi[m]=MF(ah,ufl[q],aNi[m]); aNi[m]=MF(al,ufh[q],aNi[m]);
                    }
                }
                if (g >= TSTEPS + 1){
                    oa[m]=MF(ah,rwh[q],oa[m]); oa[m]=MF(ah,rwl[q],oa[m]); oa[m]=MF(al,rwh[q],oa[m]);
                }
            }
        }

        // ---- K-reduction partials (double-buffered -> single barrier/step) ----
        if (!last){
            f32x4* rp = s_redv + ((size_t)p*RED_SLOTS + wv*8)*64 + lane;
            rp[0]   = aR[0]; rp[64]  = aZ[0]; rp[128] = aNi[0]; rp[192] = aNh[0];
            rp[256] = aR[1]; rp[320] = aZ[1]; rp[384] = aNi[1]; rp[448] = aNh[1];
        }
        if (g >= TSTEPS + 1){
            f32x4* op = s_redv + ((size_t)p*RED_SLOTS + 32 + wv*2)*64 + lane;
            op[0] = oa[0]; op[64] = oa[1];
        }
        __syncthreads();

        // ---- elementwise (all 4 waves, 2 cells each) + tagged h store + canary ----
        if (!last){
            f32x4 R = z4, Z = z4, Ni = z4, Nh = z4;
            #pragma unroll
            for (int w2 = 0; w2 < 4; ++w2){
                const f32x4* rp = s_redv + ((size_t)p*RED_SLOTS + w2*8 + mw*4)*64 + lane;
                R += rp[0]; Z += rp[64]; Ni += rp[128]; Nh += rp[192];
            }
            #define EW(J, HW, RO) { \
                float r = sigmoidf_(R[J]); \
                float z = sigmoidf_(Z[J]); \
                float n = tanhf(Ni[J] + r*Nh[J]); \
                float hold = bf16_to_f((unsigned short)((HW) >> 16)) \
                           + bf16_to_f((unsigned short)((HW) & 0xFFFFu)); \
                float hv = (1.0f - z)*n + z*hold; \
                unsigned short p1 = bf16_rne(hv); \
                unsigned short p0 = bf16_rne(hv - bf16_to_f(p1)); \
                store_sys_b32u(hout + (size_t)(bg*32 + hr0 + RO)*256 + hcol, \
                               (((unsigned)p1) << 16) | ((unsigned)(p0 & 0xFFFCu)) | otag); }
            if (jb == 0){ EW(0, ho0, 0); EW(1, ho1, 1); }
            else        { EW(2, ho0, 0); EW(3, ho1, 1); }
            #undef EW
            if (lane == 0) store_sys_b32u(mycan, (unsigned)(g + 1));
        }

        // ---- out_{g-129} = H @ regW^T + regb (dec; K-reduced across waves) ----
        if (g >= TSTEPS + 1 && wv >= 2){
            const int m2 = wv - 2;
            float b3 = s_b3[lcol & 3];
            f32x4 ot = {b3, b3, b3, b3};
            #pragma unroll
            for (int w2 = 0; w2 < 4; ++w2)
                ot += s_redv[((size_t)p*RED_SLOTS + 32 + w2*2 + m2)*64 + lane];
            if (lcol < 4){
                const int oidx = g - TSTEPS - 1;
                #pragma unroll
                for (int j = 0; j < 4; ++j)
                    out[(size_t)(bg*32 + m2*16 + quad*4 + j)*(TSTEPS*Fsz)
                        + (size_t)oidx*Fsz + hb*4 + lcol] = ot[j];
            }
        }
    }
}

extern "C" void kernel_launch(void* const* d_in, const int* in_sizes, int n_in,
                              void* d_out, int out_size, void* d_ws, size_t ws_size,
                              hipStream_t stream)
{
    (void)in_sizes; (void)n_in; (void)out_size; (void)ws_size;
    const float* x    = (const float*)d_in[0];
    const float* eWih = (const float*)d_in[1];
    const float* eWhh = (const float*)d_in[2];
    const float* ebih = (const float*)d_in[3];
    const float* ebhh = (const float*)d_in[4];
    const float* dWih = (const float*)d_in[5];
    const float* dWhh = (const float*)d_in[6];
    const float* dbih = (const float*)d_in[7];
    const float* dbhh = (const float*)d_in[8];
    const float* regW = (const float*)d_in[9];
    const float* regb = (const float*)d_in[10];
    float* out = (float*)d_out;

    unsigned* hbuf = (unsigned*)d_ws;                    // 2 slots of 512x256 packed bf16-pairs
    float* Mw    = (float*)d_ws + 2*Bsz*Hsz;             // 768*256
    float* gi0   = Mw + G3*Hsz;                          // 512*768
    float* cfold = gi0 + Bsz*G3;                         // 768 (+pad)
    unsigned* canary = (unsigned*)(cfold + 1024);        // 16 bg x 64 wave-canaries, 16B stride

    // slot0 = h^0 = 0 (tag 0 == tag(gen 0));  slot1 = 0x03 bytes (tag 3 != tag(gen 1)=0)
    hipMemsetAsync(hbuf, 0, (size_t)Bsz*Hsz*sizeof(unsigned), stream);
    hipMemsetAsync(hbuf + (size_t)Bsz*Hsz, 3, (size_t)Bsz*Hsz*sizeof(unsigned), stream);
    hipMemsetAsync(canary, 0, (size_t)BG*64*4*sizeof(unsigned), stream);

    hipLaunchKernelGGL(gru_setup, dim3(2307), dim3(256), 0, stream,
                       x, dWih, dbih, regW, regb, Mw, cfold, gi0);

    hipFuncSetAttribute((const void*)gru_persistent,
                        hipFuncAttributeMaxDynamicSharedMemorySize, SMEM_BYTES);

    void* args[] = { (void*)&x, (void*)&eWih, (void*)&eWhh, (void*)&ebih, (void*)&ebhh,
                     (void*)&dWhh, (void*)&dbhh, (void*)&Mw, (void*)&cfold, (void*)&gi0,
                     (void*)&regW, (void*)&regb, (void*)&hbuf, (void*)&canary, (void*)&out };
    hipError_t rc = hipLaunchCooperativeKernel((const void*)gru_persistent,
                                               dim3(NBLK), dim3(NTHR), args,
                                               SMEM_BYTES, stream);
    if (rc != hipSuccess) {
        hipLaunchKernelGGL(gru_persistent, dim3(NBLK), dim3(NTHR), SMEM_BYTES, stream,
                           x, eWih, eWhh, ebih, ebhh, dWhh, dbhh, Mw, cfold, gi0,
                           regW, regb, hbuf, canary, out);
    }
}

// Round 3
// 1161.901 us; speedup vs baseline: 1.1424x; 1.1424x over previous
//
#include <hip/hip_runtime.h>
#include <math.h>

#define Bsz 512
#define Fsz 64
#define Hsz 256
#define TSTEPS 128
#define G3 768

#define BG 16            // batch groups (32 rows each)
#define HB 16            // hidden-slice blocks (16 cols x 3 gates each)
#define NBLK 256
#define NTHR 256

// LDS: single-buffered K-reduction scratch (two barriers/step) + biases.
// 32 gate slots (4 waves x 2 m x 4 gates) + 8 oa slots; slot = 64 lanes x f32x4
#define RED_SLOTS 40
#define OFF_B (RED_SLOTS*64*16)        // 40960
#define SMEM_BYTES (OFF_B + 512)

typedef float f32x4 __attribute__((ext_vector_type(4)));
typedef short s16x8 __attribute__((ext_vector_type(8)));
typedef unsigned int  u32x4 __attribute__((ext_vector_type(4)));

#define MF(a,b,c) __builtin_amdgcn_mfma_f32_16x16x32_bf16(a,b,c,0,0,0)

static __device__ __forceinline__ unsigned short bf16_rne(float f){
    union { float f; unsigned u; } v; v.f = f;
    return (unsigned short)((v.u + 0x7FFFu + ((v.u >> 16) & 1u)) >> 16);
}
static __device__ __forceinline__ float bf16_to_f(unsigned short h){
    union { unsigned u; float f; } v; v.u = ((unsigned)h) << 16; return v.f;
}
static __device__ __forceinline__ void split8(const float* p, s16x8& hi, s16x8& lo){
    #pragma unroll
    for (int t = 0; t < 8; ++t){
        float f = p[t];
        unsigned short h = bf16_rne(f);
        hi[t] = (short)h;
        lo[t] = (short)bf16_rne(f - bf16_to_f(h));
    }
}
static __device__ __forceinline__ float sigmoidf_(float v){ return 1.0f/(1.0f + expf(-v)); }

// ---- MALL-coherent (cache-bypass) ops: sc0 sc1 = system scope, skip L1+L2.
// ---- This is the R0-verified coherence recipe; used unconditionally.
__device__ __forceinline__ u32x4 load_sys_b128u(const unsigned* p){
    u32x4 r;
    asm volatile("global_load_dwordx4 %0, %1, off sc0 sc1" : "=v"(r) : "v"(p) : "memory");
    return r;
}
__device__ __forceinline__ unsigned load_sys_b32u_nw(const unsigned* p){
    unsigned r;
    asm volatile("global_load_dword %0, %1, off sc0 sc1" : "=v"(r) : "v"(p) : "memory");
    return r;
}
__device__ __forceinline__ void store_sys_b32u(unsigned* p, unsigned v){
    asm volatile("global_store_dword %0, %1, off sc0 sc1" :: "v"(p), "v"(v) : "memory");
}
__device__ __forceinline__ int load_sys_i32(const int* p){
    int r;
    asm volatile("global_load_dword %0, %1, off sc0 sc1\n\ts_waitcnt vmcnt(0)"
                 : "=v"(r) : "v"(p) : "memory");
    return r;
}
__device__ __forceinline__ void waitcnt0(){ asm volatile("s_waitcnt vmcnt(0)" ::: "memory"); }
// register barrier: pins ALU uses of asm-load results after a preceding waitcnt
__device__ __forceinline__ void regbar(u32x4& v){ asm volatile("" : "+v"(v)); }
__device__ __forceinline__ void regbar32(unsigned& v){ asm volatile("" : "+v"(v)); }

static __device__ __forceinline__ void unpack8(const u32x4 a, const u32x4 b, s16x8& hi, s16x8& lo){
    #pragma unroll
    for (int e = 0; e < 4; ++e){
        hi[e]   = (short)(a[e] >> 16);  lo[e]   = (short)(a[e] & 0xFFFFu);
        hi[4+e] = (short)(b[e] >> 16);  lo[4+e] = (short)(b[e] & 0xFFFFu);
    }
}

// ---------------- setup: M = dec_Wih@reg_W, cfold = dec_Wih@reg_b + dec_bih,
// ---------------- gi0 = x[:,127,:]@dec_Wih.T + dec_bih
extern "C" __global__ void gru_setup(const float* __restrict__ x,
                                     const float* __restrict__ dWih,
                                     const float* __restrict__ dbih,
                                     const float* __restrict__ regW,
                                     const float* __restrict__ regb,
                                     float* __restrict__ Mw,
                                     float* __restrict__ cfold,
                                     float* __restrict__ gi0)
{
    int idx = blockIdx.x*blockDim.x + threadIdx.x;
    if (idx < G3*Hsz) {
        int g = idx >> 8, j = idx & 255;
        float a = 0.f;
        #pragma unroll 8
        for (int f = 0; f < Fsz; ++f) a += dWih[g*Fsz + f]*regW[f*Hsz + j];
        Mw[idx] = a;
    } else if (idx < G3*Hsz + G3) {
        int g = idx - G3*Hsz;
        float a = dbih[g];
        #pragma unroll 8
        for (int f = 0; f < Fsz; ++f) a += dWih[g*Fsz + f]*regb[f];
        cfold[g] = a;
    } else {
        int e = idx - (G3*Hsz + G3);
        if (e < Bsz*G3) {
            int b = e / G3, g = e - b*G3;
            const float* xp = x + (size_t)b*(256*64) + 127*64;
            float a = dbih[g];
            #pragma unroll 8
            for (int f = 0; f < Fsz; ++f) a += xp[f]*dWih[g*Fsz + f];
            gi0[e] = a;
        }
    }
}

// ---------------- persistent GRU kernel ----------------
// Per-step protocol: h stores (sc0 sc1) -> s_waitcnt vmcnt(0) (stores acked at
// MALL) -> per-wave canary = g+1 (plain sc0 sc1 store, no atomic). Consumers:
// poll the 64 per-wave canaries (1 dword/lane, __all over the wave) until all
// >= g, then load fragments ONCE and drain with a single vmcnt(0).
// Intra-block h visibility comes from the end-of-iteration barrier B2.
// Ring-2 slot safety: a block writes gen g+1 (slot (g+1)&1) only after its
// canary wait saw every producer's canary >= g, which in program order implies
// those producers' READS of gen g-1 (same slot) completed.
extern "C" __global__ void __launch_bounds__(NTHR, 1)
gru_persistent(const float* __restrict__ x,
               const float* __restrict__ eWih, const float* __restrict__ eWhh,
               const float* __restrict__ ebih, const float* __restrict__ ebhh,
               const float* __restrict__ dWhh, const float* __restrict__ dbhh,
               const float* __restrict__ Mw,   const float* __restrict__ cfold,
               const float* __restrict__ gi0,  const float* __restrict__ regW,
               const float* __restrict__ regb,
               unsigned* __restrict__ hbuf, unsigned* __restrict__ canary,
               float* __restrict__ out)
{
    extern __shared__ char lds[];
    f32x4* s_redv = (f32x4*)lds;
    float* s_bias = (float*)(lds + OFF_B);    // enc: [0..63]; dec: bc [0..47]
    float* s_dbh  = s_bias + 64;              // dec: dbhh slices
    float* s_b3   = s_bias + 112;             // reg_b slice [0..3]

    const int tid  = threadIdx.x;
    const int wv   = tid >> 6;        // wave 0..3 (K-split-4 over K=256)
    const int lane = tid & 63;
    const int quad = lane >> 4;
    const int lcol = lane & 15;
    const int bg   = blockIdx.x & 15; // same-bg blocks adjacent-in-XCD under round-robin (perf only)
    const int hb   = blockIdx.x >> 4;
    const int hcol = hb*16 + lcol;
    const int mw   = wv & 1;          // this wave's m for x-GEMM + elementwise
    const int kh   = wv >> 1;         // this wave's k-half for x-GEMM
    const int jb   = kh*2;            // elementwise j-base (0 or 2)
    const int hr0  = mw*16 + quad*4 + jb;   // first of this thread's 2 output rows
    const f32x4 z4 = {0.f, 0.f, 0.f, 0.f};

    // per-wave canary word (monotone gen counter); 16B stride
    unsigned* mycan = canary + ((size_t)bg*64 + hb*4 + wv)*4;
    const int* canp = (const int*)canary + ((size_t)bg*64 + lane)*4;
    const int  can_mine = ((lane >> 2) == hb);   // own block handled by barrier B2

    // ---- encoder weight fragments (B-operand: n=lcol -> row of W, k contiguous) ----
    s16x8 wfh[3][2], wfl[3][2];   // Whh (enc), then dec Whh / combined Whh+M
    s16x8 ufh[3], ufl[3];         // enc Wih (this wave's k-half); dec: [0..1] = M (n-gate)
    s16x8 rwh[2], rwl[2];         // dec: regW rows hb*4+(lcol&3), this wave's k-slice
    #pragma unroll
    for (int g = 0; g < 3; ++g){
        #pragma unroll
        for (int q = 0; q < 2; ++q)
            split8(eWhh + (size_t)(g*256 + hcol)*256 + wv*64 + q*32 + quad*8,
                   wfh[g][q], wfl[g][q]);
        split8(eWih + (size_t)(g*256 + hcol)*64 + kh*32 + quad*8, ufh[g], ufl[g]);
    }
    if (tid < 16){
        int c = hb*16 + tid;
        s_bias[tid]    = ebih[c]       + ebhh[c];
        s_bias[16+tid] = ebih[256+c]   + ebhh[256+c];
        s_bias[32+tid] = ebih[512+c];
        s_bias[48+tid] = ebhh[512+c];
    }
    __syncthreads();

    // =================== unified generation loop ===================
    // g=0..127: encoder; g=128..255: decoder; g=256: final out only
    for (int g = 0; g <= 2*TSTEPS; ++g){
        const bool enc  = (g < TSTEPS);
        const bool last = (g == 2*TSTEPS);
        const unsigned* hin = hbuf + (size_t)(g & 1)*Bsz*Hsz;
        unsigned* hout = hbuf + (size_t)((g+1) & 1)*Bsz*Hsz;

        // ---- enc->dec transition: reload weights/biases (one-time) ----
        if (g == TSTEPS){
            #pragma unroll
            for (int gg = 0; gg < 3; ++gg)
                #pragma unroll
                for (int q = 0; q < 2; ++q)
                    split8(dWhh + (size_t)(gg*256 + hcol)*256 + wv*64 + q*32 + quad*8,
                           wfh[gg][q], wfl[gg][q]);
            #pragma unroll
            for (int q = 0; q < 2; ++q){
                split8(Mw   + (size_t)(2*256 + hcol)*256 + wv*64 + q*32 + quad*8,
                       ufh[q], ufl[q]);
                split8(regW + (size_t)(hb*4 + (lcol & 3))*256 + wv*64 + q*32 + quad*8,
                       rwh[q], rwl[q]);
            }
            if (tid < 16){
                int c = hb*16 + tid;
                s_bias[tid]    = cfold[c]     + dbhh[c];
                s_bias[16+tid] = cfold[256+c] + dbhh[256+c];
                s_bias[32+tid] = cfold[512+c];
                s_dbh[tid]     = dbhh[c];
                s_dbh[16+tid]  = dbhh[256+c];
                s_dbh[32+tid]  = dbhh[512+c];
            }
            if (tid < 4) s_b3[tid] = regb[hb*4 + tid];
            __syncthreads();
        }
        if (g == TSTEPS + 1){
            // fold M into Whh for R,Z gates: one 3-term MFMA group instead of two
            #pragma unroll
            for (int gg = 0; gg < 2; ++gg)
                #pragma unroll
                for (int q = 0; q < 2; ++q){
                    float tmp[8];
                    const float* pa = dWhh + (size_t)(gg*256 + hcol)*256 + wv*64 + q*32 + quad*8;
                    const float* pb = Mw   + (size_t)(gg*256 + hcol)*256 + wv*64 + q*32 + quad*8;
                    #pragma unroll
                    for (int t2 = 0; t2 < 8; ++t2) tmp[t2] = pa[t2] + pb[t2];
                    split8(tmp, wfh[gg][q], wfl[gg][q]);
                }
        }

        // ---- accumulator init (wave 0 carries biases / gi0; others zero) ----
        f32x4 aR[2], aZ[2], aNi[2], aNh[2], oa[2];
        oa[0] = z4; oa[1] = z4;
        if (wv == 0 && !last){
            if (g == TSTEPS){
                #pragma unroll
                for (int m = 0; m < 2; ++m)
                    #pragma unroll
                    for (int j = 0; j < 4; ++j){
                        int grow_ = bg*32 + m*16 + quad*4 + j;
                        const float* gp = gi0 + (size_t)grow_*G3 + hcol;
                        aR[m][j]  = gp[0]   + s_dbh[lcol];
                        aZ[m][j]  = gp[256] + s_dbh[16+lcol];
                        aNi[m][j] = gp[512];
                        aNh[m][j] = s_dbh[32+lcol];
                    }
            } else {
                float bR = s_bias[lcol], bZ = s_bias[16+lcol], bNi = s_bias[32+lcol];
                float bNh = enc ? s_bias[48+lcol] : s_dbh[32+lcol];
                #pragma unroll
                for (int m = 0; m < 2; ++m){
                    aR[m] = (f32x4){bR,bR,bR,bR}; aZ[m] = (f32x4){bZ,bZ,bZ,bZ};
                    aNi[m] = (f32x4){bNi,bNi,bNi,bNi}; aNh[m] = (f32x4){bNh,bNh,bNh,bNh};
                }
            }
        } else {
            #pragma unroll
            for (int m = 0; m < 2; ++m){ aR[m]=z4; aZ[m]=z4; aNi[m]=z4; aNh[m]=z4; }
        }

        // ---- x loads (enc): plain cached, issued before the wait ----
        f32x4 xv0, xv1;
        if (enc){
            const float* xp = x + (size_t)(bg*32 + mw*16 + lcol)*(256*64)
                                + (size_t)g*64 + kh*32 + quad*8;
            xv0 = *(const f32x4*)xp;
            xv1 = *(const f32x4*)(xp + 4);
        }

        // ---- canary wait: authoritative (producers ack h stores before posting) ----
        if (g){
            while (1){
                int v = load_sys_i32(canp);
                if (__all(can_mine | (v >= g))) break;
                __builtin_amdgcn_s_sleep(1);
            }
        }

        // ---- issue A-fragment loads ONCE (per-lane, straight from MALL) ----
        const unsigned* ab = hin + (size_t)(bg*32 + lcol)*256 + wv*64 + quad*8;
        u32x4 t[8];
        #pragma unroll
        for (int m = 0; m < 2; ++m)
            #pragma unroll
            for (int q = 0; q < 2; ++q)
                #pragma unroll
                for (int h4 = 0; h4 < 2; ++h4)
                    t[m*4+q*2+h4] = load_sys_b128u(ab + m*4096 + q*32 + h4*4);
        const unsigned* hoA = hin + (size_t)(bg*32 + hr0)*256 + hcol;
        unsigned ho0 = load_sys_b32u_nw(hoA);
        unsigned ho1 = load_sys_b32u_nw(hoA + 256);

        // ---- x-GEMM while fragments are in flight (enc; m=mw, k-half=kh) ----
        if (enc){
            float xf[8];
            #pragma unroll
            for (int e = 0; e < 4; ++e){ xf[e] = xv0[e]; xf[4+e] = xv1[e]; }
            s16x8 xh, xl;
            split8(xf, xh, xl);
            #define XMF(M) { \
                aR[M] =MF(xh,ufh[0],aR[M]);  aR[M] =MF(xh,ufl[0],aR[M]);  aR[M] =MF(xl,ufh[0],aR[M]);  \
                aZ[M] =MF(xh,ufh[1],aZ[M]);  aZ[M] =MF(xh,ufl[1],aZ[M]);  aZ[M] =MF(xl,ufh[1],aZ[M]);  \
                aNi[M]=MF(xh,ufh[2],aNi[M]); aNi[M]=MF(xh,ufl[2],aNi[M]); aNi[M]=MF(xl,ufh[2],aNi[M]); }
            if (mw == 0) XMF(0) else XMF(1)
            #undef XMF
        }

        // ---- single drain; pin unpack after it ----
        waitcnt0();
        #pragma unroll
        for (int jj = 0; jj < 8; ++jj) regbar(t[jj]);
        regbar32(ho0); regbar32(ho1);

        // ---- h-GEMMs on this wave's K-slice (in-register unpack, no LDS) ----
        #pragma unroll
        for (int m = 0; m < 2; ++m){
            #pragma unroll
            for (int q = 0; q < 2; ++q){
                s16x8 ah, al;
                unpack8(t[m*4+q*2], t[m*4+q*2+1], ah, al);
                if (!last){
                    aR[m]=MF(ah,wfh[0][q],aR[m]); aR[m]=MF(ah,wfl[0][q],aR[m]); aR[m]=MF(al,wfh[0][q],aR[m]);
                    aZ[m]=MF(ah,wfh[1][q],aZ[m]); aZ[m]=MF(ah,wfl[1][q],aZ[m]); aZ[m]=MF(al,wfh[1][q],aZ[m]);
                    aNh[m]=MF(ah,wfh[2][q],aNh[m]); aNh[m]=MF(ah,wfl[2][q],aNh[m]); aNh[m]=MF(al,wfh[2][q],aNh[m]);
                    if (!enc && g > TSTEPS){
                        aNi[m]=MF(ah,ufh[q],aNi[m]); aNi[m]=MF(ah,ufl[q],aNi[m]); aNi[m]=MF(al,ufh[q],aNi[m]);
                    }
                }
                if (g >= TSTEPS + 1){
                    oa[m]=MF(ah,rwh[q],oa[m]); oa[m]=MF(ah,rwl[q],oa[m]); oa[m]=MF(al,rwh[q],oa[m]);
                }
            }
        }

        // ---- K-reduction partials (single buffer; two barriers/step) ----
        if (!last){
            f32x4* rp = s_redv + (size_t)(wv*8)*64 + lane;
            rp[0]   = aR[0]; rp[64]  = aZ[0]; rp[128] = aNi[0]; rp[192] = aNh[0];
            rp[256] = aR[1]; rp[320] = aZ[1]; rp[384] = aNi[1]; rp[448] = aNh[1];
        }
        if (g >= TSTEPS + 1){
            f32x4* op = s_redv + (size_t)(32 + wv*2)*64 + lane;
            op[0] = oa[0]; op[64] = oa[1];
        }
        __syncthreads();   // B1: partials visible

        // ---- elementwise (all 4 waves, 2 cells each) + h stores (no wait yet) ----
        if (!last){
            f32x4 R = z4, Z = z4, Ni = z4, Nh = z4;
            #pragma unroll
            for (int w2 = 0; w2 < 4; ++w2){
                const f32x4* rp = s_redv + (size_t)(w2*8 + mw*4)*64 + lane;
                R += rp[0]; Z += rp[64]; Ni += rp[128]; Nh += rp[192];
            }
            #define EW(J, HW, RO) { \
                float r = sigmoidf_(R[J]); \
                float z = sigmoidf_(Z[J]); \
                float n = tanhf(Ni[J] + r*Nh[J]); \
                float hold = bf16_to_f((unsigned short)((HW) >> 16)) \
                           + bf16_to_f((unsigned short)((HW) & 0xFFFFu)); \
                float hv = (1.0f - z)*n + z*hold; \
                unsigned short p1 = bf16_rne(hv); \
                unsigned short p0 = bf16_rne(hv - bf16_to_f(p1)); \
                store_sys_b32u(hout + (size_t)(bg*32 + hr0 + RO)*256 + hcol, \
                               (((unsigned)p1) << 16) | (unsigned)p0); }
            if (jb == 0){ EW(0, ho0, 0); EW(1, ho1, 1); }
            else        { EW(2, ho0, 0); EW(3, ho1, 1); }
            #undef EW
        }

        // ---- out_{g-129} = H @ regW^T + regb (overlaps the store-ack) ----
        if (g >= TSTEPS + 1 && wv >= 2){
            const int m2 = wv - 2;
            float b3 = s_b3[lcol & 3];
            f32x4 ot = {b3, b3, b3, b3};
            #pragma unroll
            for (int w2 = 0; w2 < 4; ++w2)
                ot += s_redv[(size_t)(32 + w2*2 + m2)*64 + lane];
            if (lcol < 4){
                const int oidx = g - TSTEPS - 1;
                #pragma unroll
                for (int j = 0; j < 4; ++j)
                    out[(size_t)(bg*32 + m2*16 + quad*4 + j)*(TSTEPS*Fsz)
                        + (size_t)oidx*Fsz + hb*4 + lcol] = ot[j];
            }
        }

        // ---- ack h stores at the MALL, then release this wave's canary ----
        if (!last){
            waitcnt0();
            if (lane == 0) store_sys_b32u(mycan, (unsigned)(g + 1));
        }
        __syncthreads();   // B2: intra-block h visibility + LDS reuse safety
    }
}

extern "C" void kernel_launch(void* const* d_in, const int* in_sizes, int n_in,
                              void* d_out, int out_size, void* d_ws, size_t ws_size,
                              hipStream_t stream)
{
    (void)in_sizes; (void)n_in; (void)out_size; (void)ws_size;
    const float* x    = (const float*)d_in[0];
    const float* eWih = (const float*)d_in[1];
    const float* eWhh = (const float*)d_in[2];
    const float* ebih = (const float*)d_in[3];
    const float* ebhh = (const float*)d_in[4];
    const float* dWih = (const float*)d_in[5];
    const float* dWhh = (const float*)d_in[6];
    const float* dbih = (const float*)d_in[7];
    const float* dbhh = (const float*)d_in[8];
    const float* regW = (const float*)d_in[9];
    const float* regb = (const float*)d_in[10];
    float* out = (float*)d_out;

    unsigned* hbuf = (unsigned*)d_ws;                    // 2 slots of 512x256 packed bf16-pairs
    float* Mw    = (float*)d_ws + 2*Bsz*Hsz;             // 768*256
    float* gi0   = Mw + G3*Hsz;                          // 512*768
    float* cfold = gi0 + Bsz*G3;                         // 768 (+pad)
    unsigned* canary = (unsigned*)(cfold + 1024);        // 16 bg x 64 wave-canaries, 16B stride

    hipMemsetAsync(hbuf, 0, (size_t)Bsz*Hsz*sizeof(unsigned), stream); // h^0 = 0
    hipMemsetAsync(canary, 0, (size_t)BG*64*4*sizeof(unsigned), stream);

    hipLaunchKernelGGL(gru_setup, dim3(2307), dim3(256), 0, stream,
                       x, dWih, dbih, regW, regb, Mw, cfold, gi0);

    hipFuncSetAttribute((const void*)gru_persistent,
                        hipFuncAttributeMaxDynamicSharedMemorySize, SMEM_BYTES);

    void* args[] = { (void*)&x, (void*)&eWih, (void*)&eWhh, (void*)&ebih, (void*)&ebhh,
                     (void*)&dWhh, (void*)&dbhh, (void*)&Mw, (void*)&cfold, (void*)&gi0,
                     (void*)&regW, (void*)&regb, (void*)&hbuf, (void*)&canary, (void*)&out };
    hipError_t rc = hipLaunchCooperativeKernel((const void*)gru_persistent,
                                               dim3(NBLK), dim3(NTHR), args,
                                               SMEM_BYTES, stream);
    if (rc != hipSuccess) {
        hipLaunchKernelGGL(gru_persistent, dim3(NBLK), dim3(NTHR), SMEM_BYTES, stream,
                           x, eWih, eWhh, ebih, ebhh, dWhh, dbhh, Mw, cfold, gi0,
                           regW, regb, hbuf, canary, out);
    }
}

// Round 4
// 1080.683 us; speedup vs baseline: 1.2282x; 1.0752x over previous
//
#include <hip/hip_runtime.h>
#include <math.h>

#define Bsz 512
#define Fsz 64
#define Hsz 256
#define TSTEPS 128
#define G3 768

#define BG 16            // batch groups (32 rows each)
#define HB 16            // hidden-slice blocks (16 cols x 3 gates each)
#define NBLK 256
#define NTHR 256

// LDS: single-buffered K-reduction scratch (two barriers/step) + biases.
// 32 gate slots (4 waves x 2 m x 4 gates) + 8 oa slots; slot = 64 lanes x f32x4
#define RED_SLOTS 40
#define OFF_B (RED_SLOTS*64*16)        // 40960
#define SMEM_BYTES (OFF_B + 512)

typedef float f32x4 __attribute__((ext_vector_type(4)));
typedef short s16x8 __attribute__((ext_vector_type(8)));
typedef unsigned int  u32x4 __attribute__((ext_vector_type(4)));

#define MF(a,b,c) __builtin_amdgcn_mfma_f32_16x16x32_bf16(a,b,c,0,0,0)

static __device__ __forceinline__ unsigned short bf16_rne(float f){
    union { float f; unsigned u; } v; v.f = f;
    return (unsigned short)((v.u + 0x7FFFu + ((v.u >> 16) & 1u)) >> 16);
}
static __device__ __forceinline__ float bf16_to_f(unsigned short h){
    union { unsigned u; float f; } v; v.u = ((unsigned)h) << 16; return v.f;
}
static __device__ __forceinline__ void split8(const float* p, s16x8& hi, s16x8& lo){
    #pragma unroll
    for (int t = 0; t < 8; ++t){
        float f = p[t];
        unsigned short h = bf16_rne(f);
        hi[t] = (short)h;
        lo[t] = (short)bf16_rne(f - bf16_to_f(h));
    }
}
// fast transcendentals: v_exp_f32 (2^x) + v_rcp_f32; ~2ulp, far below bf16 noise
static __device__ __forceinline__ float sigmoidf_(float v){
    return __builtin_amdgcn_rcpf(1.0f + __builtin_amdgcn_exp2f(-1.44269504f*v));
}
static __device__ __forceinline__ float tanhf_(float v){
    return 1.0f - 2.0f*__builtin_amdgcn_rcpf(1.0f + __builtin_amdgcn_exp2f(2.88539008f*v));
}

// ---- MALL-coherent (cache-bypass) ops: sc0 sc1 = system scope, skip L1+L2 ----
__device__ __forceinline__ u32x4 load_sys_b128u(const unsigned* p){
    u32x4 r;
    asm volatile("global_load_dwordx4 %0, %1, off sc0 sc1" : "=v"(r) : "v"(p) : "memory");
    return r;
}
__device__ __forceinline__ unsigned load_sys_b32u_nw(const unsigned* p){
    unsigned r;
    asm volatile("global_load_dword %0, %1, off sc0 sc1" : "=v"(r) : "v"(p) : "memory");
    return r;
}
__device__ __forceinline__ void store_sys_b32u(unsigned* p, unsigned v){
    asm volatile("global_store_dword %0, %1, off sc0 sc1" :: "v"(p), "v"(v) : "memory");
}
__device__ __forceinline__ int load_sys_i32(const int* p){
    int r;
    asm volatile("global_load_dword %0, %1, off sc0 sc1\n\ts_waitcnt vmcnt(0)"
                 : "=v"(r) : "v"(p) : "memory");
    return r;
}
__device__ __forceinline__ void waitcnt0(){ asm volatile("s_waitcnt vmcnt(0)" ::: "memory"); }
// register barrier: pins ALU uses of asm-load results after a preceding waitcnt
__device__ __forceinline__ void regbar(u32x4& v){ asm volatile("" : "+v"(v)); }
__device__ __forceinline__ void regbar32(unsigned& v){ asm volatile("" : "+v"(v)); }

static __device__ __forceinline__ void unpack8(const u32x4 a, const u32x4 b, s16x8& hi, s16x8& lo){
    #pragma unroll
    for (int e = 0; e < 4; ++e){
        hi[e]   = (short)(a[e] >> 16);  lo[e]   = (short)(a[e] & 0xFFFFu);
        hi[4+e] = (short)(b[e] >> 16);  lo[4+e] = (short)(b[e] & 0xFFFFu);
    }
}

// ---------------- setup: M = dec_Wih@reg_W, cfold = dec_Wih@reg_b + dec_bih,
// ---------------- gi0 = x[:,127,:]@dec_Wih.T + dec_bih
extern "C" __global__ void gru_setup(const float* __restrict__ x,
                                     const float* __restrict__ dWih,
                                     const float* __restrict__ dbih,
                                     const float* __restrict__ regW,
                                     const float* __restrict__ regb,
                                     float* __restrict__ Mw,
                                     float* __restrict__ cfold,
                                     float* __restrict__ gi0)
{
    int idx = blockIdx.x*blockDim.x + threadIdx.x;
    if (idx < G3*Hsz) {
        int g = idx >> 8, j = idx & 255;
        float a = 0.f;
        #pragma unroll 8
        for (int f = 0; f < Fsz; ++f) a += dWih[g*Fsz + f]*regW[f*Hsz + j];
        Mw[idx] = a;
    } else if (idx < G3*Hsz + G3) {
        int g = idx - G3*Hsz;
        float a = dbih[g];
        #pragma unroll 8
        for (int f = 0; f < Fsz; ++f) a += dWih[g*Fsz + f]*regb[f];
        cfold[g] = a;
    } else {
        int e = idx - (G3*Hsz + G3);
        if (e < Bsz*G3) {
            int b = e / G3, g = e - b*G3;
            const float* xp = x + (size_t)b*(256*64) + 127*64;
            float a = dbih[g];
            #pragma unroll 8
            for (int f = 0; f < Fsz; ++f) a += xp[f]*dWih[g*Fsz + f];
            gi0[e] = a;
        }
    }
}

// ---------------- persistent GRU kernel: tags authoritative, flags as hint ----------------
// h word = hi_bf16<<16 | (lo_bf16 & ~3) | tag2, tag2 = (gen>>1)&3, slot = gen&1.
// Producer: EW -> tagged h stores -> flag=g+1 (NO ack). Consumer: speculative
// fragment loads + one tag check; on miss, poll the 16 flags of its 4 RELEVANT
// producer blocks (wave wv's K-slice only reads hb' in [wv*4,wv*4+4)), then
// reload+recheck. Ring-2 slot safety (no acks needed): B stores h^{g+2} only
// after verifying tags of h^{g+1} from every P, which implies P finished
// verified-reading h^g -> no live reader of the slot being overwritten.
extern "C" __global__ void __launch_bounds__(NTHR, 1)
gru_persistent(const float* __restrict__ x,
               const float* __restrict__ eWih, const float* __restrict__ eWhh,
               const float* __restrict__ ebih, const float* __restrict__ ebhh,
               const float* __restrict__ dWhh, const float* __restrict__ dbhh,
               const float* __restrict__ Mw,   const float* __restrict__ cfold,
               const float* __restrict__ gi0,  const float* __restrict__ regW,
               const float* __restrict__ regb,
               unsigned* __restrict__ hbuf, unsigned* __restrict__ canary,
               float* __restrict__ out)
{
    extern __shared__ char lds[];
    f32x4* s_redv = (f32x4*)lds;
    float* s_bias = (float*)(lds + OFF_B);    // enc: [0..63]; dec: bc [0..47]
    float* s_dbh  = s_bias + 64;              // dec: dbhh slices
    float* s_b3   = s_bias + 112;             // reg_b slice [0..3]

    const int tid  = threadIdx.x;
    const int wv   = tid >> 6;        // wave 0..3 (K-split-4 over K=256)
    const int lane = tid & 63;
    const int quad = lane >> 4;
    const int lcol = lane & 15;
    const int bg   = blockIdx.x & 15;
    const int hb   = blockIdx.x >> 4;
    const int hcol = hb*16 + lcol;
    const int mw   = wv & 1;          // this wave's m for x-GEMM + elementwise
    const int kh   = wv >> 1;         // this wave's k-half for x-GEMM
    const int jb   = kh*2;            // elementwise j-base (0 or 2)
    const int hr0  = mw*16 + quad*4 + jb;   // first of this thread's 2 output rows
    const f32x4 z4 = {0.f, 0.f, 0.f, 0.f};

    // per-wave flag word (monotone gen counter); 16B stride
    unsigned* mycan = canary + ((size_t)bg*64 + hb*4 + wv)*4;
    // this wave's RELEVANT producer flags: f = wv*16 + (lane&15) -> hb' = wv*4 + (f&15)>>2
    const int fidx  = wv*16 + (lane & 15);
    const int* fp   = (const int*)canary + ((size_t)bg*64 + fidx)*4;
    const int fmine = ((fidx >> 2) == hb);   // own block's flags: covered by tags

    // ---- encoder weight fragments (B-operand: n=lcol -> row of W, k contiguous) ----
    s16x8 wfh[3][2], wfl[3][2];   // Whh (enc), then dec Whh / combined Whh+M
    s16x8 ufh[3], ufl[3];         // enc Wih (this wave's k-half); dec: [0..1] = M (n-gate)
    s16x8 rwh[2], rwl[2];         // dec: regW rows hb*4+(lcol&3), this wave's k-slice
    #pragma unroll
    for (int g = 0; g < 3; ++g){
        #pragma unroll
        for (int q = 0; q < 2; ++q)
            split8(eWhh + (size_t)(g*256 + hcol)*256 + wv*64 + q*32 + quad*8,
                   wfh[g][q], wfl[g][q]);
        split8(eWih + (size_t)(g*256 + hcol)*64 + kh*32 + quad*8, ufh[g], ufl[g]);
    }
    if (tid < 16){
        int c = hb*16 + tid;
        s_bias[tid]    = ebih[c]       + ebhh[c];
        s_bias[16+tid] = ebih[256+c]   + ebhh[256+c];
        s_bias[32+tid] = ebih[512+c];
        s_bias[48+tid] = ebhh[512+c];
    }
    __syncthreads();

    // =================== unified generation loop ===================
    // g=0..127: encoder; g=128..255: decoder; g=256: final out only
    for (int g = 0; g <= 2*TSTEPS; ++g){
        const bool enc  = (g < TSTEPS);
        const bool last = (g == 2*TSTEPS);
        const unsigned tag  = (unsigned)((g >> 1) & 3);
        const unsigned otag = (unsigned)(((g+1) >> 1) & 3);
        const unsigned* hin = hbuf + (size_t)(g & 1)*Bsz*Hsz;
        unsigned* hout = hbuf + (size_t)((g+1) & 1)*Bsz*Hsz;

        // ---- enc->dec transition: reload weights/biases (one-time) ----
        if (g == TSTEPS){
            #pragma unroll
            for (int gg = 0; gg < 3; ++gg)
                #pragma unroll
                for (int q = 0; q < 2; ++q)
                    split8(dWhh + (size_t)(gg*256 + hcol)*256 + wv*64 + q*32 + quad*8,
                           wfh[gg][q], wfl[gg][q]);
            #pragma unroll
            for (int q = 0; q < 2; ++q){
                split8(Mw   + (size_t)(2*256 + hcol)*256 + wv*64 + q*32 + quad*8,
                       ufh[q], ufl[q]);
                split8(regW + (size_t)(hb*4 + (lcol & 3))*256 + wv*64 + q*32 + quad*8,
                       rwh[q], rwl[q]);
            }
            if (tid < 16){
                int c = hb*16 + tid;
                s_bias[tid]    = cfold[c]     + dbhh[c];
                s_bias[16+tid] = cfold[256+c] + dbhh[256+c];
                s_bias[32+tid] = cfold[512+c];
                s_dbh[tid]     = dbhh[c];
                s_dbh[16+tid]  = dbhh[256+c];
                s_dbh[32+tid]  = dbhh[512+c];
            }
            if (tid < 4) s_b3[tid] = regb[hb*4 + tid];
            __syncthreads();
        }
        if (g == TSTEPS + 1){
            // fold M into Whh for R,Z gates: one 3-term MFMA group instead of two
            #pragma unroll
            for (int gg = 0; gg < 2; ++gg)
                #pragma unroll
                for (int q = 0; q < 2; ++q){
                    float tmp[8];
                    const float* pa = dWhh + (size_t)(gg*256 + hcol)*256 + wv*64 + q*32 + quad*8;
                    const float* pb = Mw   + (size_t)(gg*256 + hcol)*256 + wv*64 + q*32 + quad*8;
                    #pragma unroll
                    for (int t2 = 0; t2 < 8; ++t2) tmp[t2] = pa[t2] + pb[t2];
                    split8(tmp, wfh[gg][q], wfl[gg][q]);
                }
        }

        // ---- accumulator init (wave 0 carries biases / gi0; others zero) ----
        f32x4 aR[2], aZ[2], aNi[2], aNh[2], oa[2];
        oa[0] = z4; oa[1] = z4;
        if (wv == 0 && !last){
            if (g == TSTEPS){
                #pragma unroll
                for (int m = 0; m < 2; ++m)
                    #pragma unroll
                    for (int j = 0; j < 4; ++j){
                        int grow_ = bg*32 + m*16 + quad*4 + j;
                        const float* gp = gi0 + (size_t)grow_*G3 + hcol;
                        aR[m][j]  = gp[0]   + s_dbh[lcol];
                        aZ[m][j]  = gp[256] + s_dbh[16+lcol];
                        aNi[m][j] = gp[512];
                        aNh[m][j] = s_dbh[32+lcol];
                    }
            } else {
                float bR = s_bias[lcol], bZ = s_bias[16+lcol], bNi = s_bias[32+lcol];
                float bNh = enc ? s_bias[48+lcol] : s_dbh[32+lcol];
                #pragma unroll
                for (int m = 0; m < 2; ++m){
                    aR[m] = (f32x4){bR,bR,bR,bR}; aZ[m] = (f32x4){bZ,bZ,bZ,bZ};
                    aNi[m] = (f32x4){bNi,bNi,bNi,bNi}; aNh[m] = (f32x4){bNh,bNh,bNh,bNh};
                }
            }
        } else {
            #pragma unroll
            for (int m = 0; m < 2; ++m){ aR[m]=z4; aZ[m]=z4; aNi[m]=z4; aNh[m]=z4; }
        }

        // ---- x loads (enc): plain cached, issued first ----
        f32x4 xv0, xv1;
        if (enc){
            const float* xp = x + (size_t)(bg*32 + mw*16 + lcol)*(256*64)
                                + (size_t)g*64 + kh*32 + quad*8;
            xv0 = *(const f32x4*)xp;
            xv1 = *(const f32x4*)(xp + 4);
        }

        // ---- SPECULATIVE fragment loads (per-lane, straight from MALL) ----
        const unsigned* ab = hin + (size_t)(bg*32 + lcol)*256 + wv*64 + quad*8;
        u32x4 t[8];
        #pragma unroll
        for (int m = 0; m < 2; ++m)
            #pragma unroll
            for (int q = 0; q < 2; ++q)
                #pragma unroll
                for (int h4 = 0; h4 < 2; ++h4)
                    t[m*4+q*2+h4] = load_sys_b128u(ab + m*4096 + q*32 + h4*4);
        const unsigned* hoA = hin + (size_t)(bg*32 + hr0)*256 + hcol;
        unsigned ho0 = load_sys_b32u_nw(hoA);
        unsigned ho1 = load_sys_b32u_nw(hoA + 256);

        // ---- x-GEMM while fragments are in flight (enc; m=mw, k-half=kh) ----
        if (enc){
            float xf[8];
            #pragma unroll
            for (int e = 0; e < 4; ++e){ xf[e] = xv0[e]; xf[4+e] = xv1[e]; }
            s16x8 xh, xl;
            split8(xf, xh, xl);
            #define XMF(M) { \
                aR[M] =MF(xh,ufh[0],aR[M]);  aR[M] =MF(xh,ufl[0],aR[M]);  aR[M] =MF(xl,ufh[0],aR[M]);  \
                aZ[M] =MF(xh,ufh[1],aZ[M]);  aZ[M] =MF(xh,ufl[1],aZ[M]);  aZ[M] =MF(xl,ufh[1],aZ[M]);  \
                aNi[M]=MF(xh,ufh[2],aNi[M]); aNi[M]=MF(xh,ufl[2],aNi[M]); aNi[M]=MF(xl,ufh[2],aNi[M]); }
            if (mw == 0) XMF(0) else XMF(1)
            #undef XMF
        }

        // ---- tag verification: fast path = one drain + one check ----
        #define UPD() { \
            _Pragma("unroll") \
            for (int jj = 0; jj < 8; ++jj) \
                if (!((done >> jj) & 1u)) \
                    if (((t[jj][0]&3u)==tag) && ((t[jj][1]&3u)==tag) && \
                        ((t[jj][2]&3u)==tag) && ((t[jj][3]&3u)==tag)) done |= (1u << jj); \
            if (!((done >> 8) & 1u) && ((ho0 & 3u) == tag)) done |= 0x100u; \
            if (!((done >> 9) & 1u) && ((ho1 & 3u) == tag)) done |= 0x200u; }

        {
            unsigned done = 0;
            waitcnt0();
            #pragma unroll
            for (int jj = 0; jj < 8; ++jj) regbar(t[jj]);
            regbar32(ho0); regbar32(ho1);
            UPD();
            if (!__all((int)(done == 0x3FFu))){
                // slow path 1: cheap flag gate on the 4 relevant producer blocks
                while (1){
                    int v = load_sys_i32(fp);
                    if (__all(fmine | (v >= g))) break;
                    __builtin_amdgcn_s_sleep(1);
                }
                // slow path 2: reload missing words, recheck (rare after gate)
                while (1){
                    #pragma unroll
                    for (int m = 0; m < 2; ++m)
                        #pragma unroll
                        for (int q = 0; q < 2; ++q)
                            #pragma unroll
                            for (int h4 = 0; h4 < 2; ++h4){
                                const int jj = m*4+q*2+h4;
                                if (!((done >> jj) & 1u))
                                    t[jj] = load_sys_b128u(ab + m*4096 + q*32 + h4*4);
                            }
                    if (!((done >> 8) & 1u)) ho0 = load_sys_b32u_nw(hoA);
                    if (!((done >> 9) & 1u)) ho1 = load_sys_b32u_nw(hoA + 256);
                    waitcnt0();
                    #pragma unroll
                    for (int jj = 0; jj < 8; ++jj) regbar(t[jj]);
                    regbar32(ho0); regbar32(ho1);
                    UPD();
                    if (__all((int)(done == 0x3FFu))) break;
                    __builtin_amdgcn_s_sleep(1);
                }
            }
        }
        #undef UPD

        // ---- h-GEMMs on this wave's K-slice (in-register unpack, no LDS) ----
        #pragma unroll
        for (int m = 0; m < 2; ++m){
            #pragma unroll
            for (int q = 0; q < 2; ++q){
                s16x8 ah, al;
                unpack8(t[m*4+q*2], t[m*4+q*2+1], ah, al);
                if (!last){
                    aR[m]=MF(ah,wfh[0][q],aR[m]); aR[m]=MF(ah,wfl[0][q],aR[m]); aR[m]=MF(al,wfh[0][q],aR[m]);
                    aZ[m]=MF(ah,wfh[1][q],aZ[m]); aZ[m]=MF(ah,wfl[1][q],aZ[m]); aZ[m]=MF(al,wfh[1][q],aZ[m]);
                    aNh[m]=MF(ah,wfh[2][q],aNh[m]); aNh[m]=MF(ah,wfl[2][q],aNh[m]); aNh[m]=MF(al,wfh[2][q],aNh[m]);
                    if (!enc && g > TSTEPS){
                        aNi[m]=MF(ah,ufh[q],aNi[m]); aNi[m]=MF(ah,ufl[q],aNi[m]); aNi[m]=MF(al,ufh[q],aNi[m]);
                    }
                }
                if (g >= TSTEPS + 1){
                    oa[m]=MF(ah,rwh[q],oa[m]); oa[m]=MF(ah,rwl[q],oa[m]); oa[m]=MF(al,rwh[q],oa[m]);
                }
            }
        }

        // ---- K-reduction partials (single buffer; two barriers/step) ----
        if (!last){
            f32x4* rp = s_redv + (size_t)(wv*8)*64 + lane;
            rp[0]   = aR[0]; rp[64]  = aZ[0]; rp[128] = aNi[0]; rp[192] = aNh[0];
            rp[256] = aR[1]; rp[320] = aZ[1]; rp[384] = aNi[1]; rp[448] = aNh[1];
        }
        if (g >= TSTEPS + 1){
            f32x4* op = s_redv + (size_t)(32 + wv*2)*64 + lane;
            op[0] = oa[0]; op[64] = oa[1];
        }
        __syncthreads();   // B1: partials visible

        // ---- elementwise (all 4 waves, 2 cells each) + tagged h stores + flag ----
        if (!last){
            f32x4 R = z4, Z = z4, Ni = z4, Nh = z4;
            #pragma unroll
            for (int w2 = 0; w2 < 4; ++w2){
                const f32x4* rp = s_redv + (size_t)(w2*8 + mw*4)*64 + lane;
                R += rp[0]; Z += rp[64]; Ni += rp[128]; Nh += rp[192];
            }
            #define EW(J, HW, RO) { \
                float r = sigmoidf_(R[J]); \
                float z = sigmoidf_(Z[J]); \
                float n = tanhf_(Ni[J] + r*Nh[J]); \
                float hold = bf16_to_f((unsigned short)((HW) >> 16)) \
                           + bf16_to_f((unsigned short)((HW) & 0xFFFFu)); \
                float hv = (1.0f - z)*n + z*hold; \
                unsigned short p1 = bf16_rne(hv); \
                unsigned short p0 = bf16_rne(hv - bf16_to_f(p1)); \
                store_sys_b32u(hout + (size_t)(bg*32 + hr0 + RO)*256 + hcol, \
                               (((unsigned)p1) << 16) | ((unsigned)(p0 & 0xFFFCu)) | otag); }
            if (jb == 0){ EW(0, ho0, 0); EW(1, ho1, 1); }
            else        { EW(2, ho0, 0); EW(3, ho1, 1); }
            #undef EW
            // flag = hint only (tags are authoritative): post immediately, no ack
            if (lane == 0) store_sys_b32u(mycan, (unsigned)(g + 1));
        }

        // ---- out_{g-129} = H @ regW^T + regb ----
        if (g >= TSTEPS + 1 && wv >= 2){
            const int m2 = wv - 2;
            float b3 = s_b3[lcol & 3];
            f32x4 ot = {b3, b3, b3, b3};
            #pragma unroll
            for (int w2 = 0; w2 < 4; ++w2)
                ot += s_redv[(size_t)(32 + w2*2 + m2)*64 + lane];
            if (lcol < 4){
                const int oidx = g - TSTEPS - 1;
                #pragma unroll
                for (int j = 0; j < 4; ++j)
                    out[(size_t)(bg*32 + m2*16 + quad*4 + j)*(TSTEPS*Fsz)
                        + (size_t)oidx*Fsz + hb*4 + lcol] = ot[j];
            }
        }
        __syncthreads();   // B2: LDS reuse safety
    }
}

extern "C" void kernel_launch(void* const* d_in, const int* in_sizes, int n_in,
                              void* d_out, int out_size, void* d_ws, size_t ws_size,
                              hipStream_t stream)
{
    (void)in_sizes; (void)n_in; (void)out_size; (void)ws_size;
    const float* x    = (const float*)d_in[0];
    const float* eWih = (const float*)d_in[1];
    const float* eWhh = (const float*)d_in[2];
    const float* ebih = (const float*)d_in[3];
    const float* ebhh = (const float*)d_in[4];
    const float* dWih = (const float*)d_in[5];
    const float* dWhh = (const float*)d_in[6];
    const float* dbih = (const float*)d_in[7];
    const float* dbhh = (const float*)d_in[8];
    const float* regW = (const float*)d_in[9];
    const float* regb = (const float*)d_in[10];
    float* out = (float*)d_out;

    unsigned* hbuf = (unsigned*)d_ws;                    // 2 slots of 512x256 packed bf16-pairs
    float* Mw    = (float*)d_ws + 2*Bsz*Hsz;             // 768*256
    float* gi0   = Mw + G3*Hsz;                          // 512*768
    float* cfold = gi0 + Bsz*G3;                         // 768 (+pad)
    unsigned* canary = (unsigned*)(cfold + 1024);        // 16 bg x 64 wave-flags, 16B stride

    // slot0 = h^0 = 0 (tag 0 == tag(gen 0)); slot1 = 0x03 bytes (tag 3 != tag(gen 1)=0)
    hipMemsetAsync(hbuf, 0, (size_t)Bsz*Hsz*sizeof(unsigned), stream);
    hipMemsetAsync(hbuf + (size_t)Bsz*Hsz, 3, (size_t)Bsz*Hsz*sizeof(unsigned), stream);
    hipMemsetAsync(canary, 0, (size_t)BG*64*4*sizeof(unsigned), stream);

    hipLaunchKernelGGL(gru_setup, dim3(2307), dim3(256), 0, stream,
                       x, dWih, dbih, regW, regb, Mw, cfold, gi0);

    hipFuncSetAttribute((const void*)gru_persistent,
                        hipFuncAttributeMaxDynamicSharedMemorySize, SMEM_BYTES);

    void* args[] = { (void*)&x, (void*)&eWih, (void*)&eWhh, (void*)&ebih, (void*)&ebhh,
                     (void*)&dWhh, (void*)&dbhh, (void*)&Mw, (void*)&cfold, (void*)&gi0,
                     (void*)&regW, (void*)&regb, (void*)&hbuf, (void*)&canary, (void*)&out };
    hipError_t rc = hipLaunchCooperativeKernel((const void*)gru_persistent,
                                               dim3(NBLK), dim3(NTHR), args,
                                               SMEM_BYTES, stream);
    if (rc != hipSuccess) {
        hipLaunchKernelGGL(gru_persistent, dim3(NBLK), dim3(NTHR), SMEM_BYTES, stream,
                           x, eWih, eWhh, ebih, ebhh, dWhh, dbhh, Mw, cfold, gi0,
                           regW, regb, hbuf, canary, out);
    }
}